// Round 9
// baseline (264.302 us; speedup 1.0000x reference)
//
#include <hip/hip_runtime.h>

// Fused MHA: X[4,2048,1024] fp32; W_K,W_Q,W_V,W_out[1024,1024]; b_out[1024].
//   1. convert_x:  X fp32 -> Xb bf16
//   2. transpose_w: W* fp32 [k][n] -> Wt bf16 [n][k]
//   3. gemm_qkv:   2-phase dbuf prefetch; Q (scaled 0.125*log2e, [s][1024]);
//                  K head-major Kh[bh][s][64]; V tiled Vb[bh][t][d][s64]
//                  Q/K use swapped-operand mfma -> vectorized epilogue stores
//   4. attn:       swapped-operand flash attn; K/V tiles staged to LDS
//                  (coalesced global_load_lds, XOR-swizzled source), dbuf
//   5. gemm_out:   2-phase dbuf + swapped-operand -> float4 stores + bias
typedef float  f32x4  __attribute__((ext_vector_type(4)));
typedef float  f32x16 __attribute__((ext_vector_type(16)));
typedef __bf16 bf16x8 __attribute__((ext_vector_type(8)));
typedef unsigned int u32x4 __attribute__((ext_vector_type(4)));

#define DIM   1024
#define SEQ   2048
#define HDIM  64

static __device__ __forceinline__ unsigned short f2bf(float f) {
  unsigned int u = __builtin_bit_cast(unsigned int, f);
  u += 0x7fffu + ((u >> 16) & 1u);   // RNE
  return (unsigned short)(u >> 16);
}

static __device__ __forceinline__ float exp2a(float x) {
#if __has_builtin(__builtin_amdgcn_exp2f)
  return __builtin_amdgcn_exp2f(x);
#else
  return exp2f(x);
#endif
}

static __device__ __forceinline__ void pswap(unsigned& a, unsigned& b) {
#if __has_builtin(__builtin_amdgcn_permlane32_swap)
  auto r = __builtin_amdgcn_permlane32_swap(a, b, false, false);
  a = r[0]; b = r[1];
#else
  asm volatile("v_permlane32_swap_b32 %0, %1" : "+v"(a), "+v"(b));
#endif
}

#define CVTPK(lo_, hi_) ({ unsigned r_;                                                 \
  asm("v_cvt_pk_bf16_f32 %0, %1, %2" : "=v"(r_) : "v"(lo_), "v"(hi_)); r_; })

// async global->LDS, 16B per lane; lds dest = wave-uniform base + lane*16
#define GLDS16(g, l)                                                                    \
  __builtin_amdgcn_global_load_lds((__attribute__((address_space(1))) void*)(g),        \
                                   (__attribute__((address_space(3))) void*)(l), 16, 0, 0)

__global__ __launch_bounds__(256) void convert_x(const float4* __restrict__ X,
                                                 ushort4* __restrict__ Xb) {
  int i = blockIdx.x * 256 + threadIdx.x;
  float4 v = X[i];
  ushort4 o;
  o.x = f2bf(v.x); o.y = f2bf(v.y); o.z = f2bf(v.z); o.w = f2bf(v.w);
  Xb[i] = o;
}

__global__ __launch_bounds__(256) void transpose_w(const float* __restrict__ WQ,
                                                   const float* __restrict__ WK,
                                                   const float* __restrict__ WV,
                                                   const float* __restrict__ WO,
                                                   unsigned short* __restrict__ WtAll) {
  const int z = blockIdx.z;
  const float* W = (z == 0) ? WQ : (z == 1) ? WK : (z == 2) ? WV : WO;
  unsigned short* Wt = WtAll + (size_t)z * (DIM * DIM);
  __shared__ float tile[32][33];
  const int tx = threadIdx.x, ty = threadIdx.y;        // 32 x 8
  const int n0 = blockIdx.x * 32, k0 = blockIdx.y * 32;
#pragma unroll
  for (int r = 0; r < 4; ++r)
    tile[ty + 8 * r][tx] = W[(size_t)(k0 + ty + 8 * r) * DIM + n0 + tx];
  __syncthreads();
#pragma unroll
  for (int r = 0; r < 4; ++r)
    Wt[(size_t)(n0 + ty + 8 * r) * DIM + k0 + tx] = f2bf(tile[tx][ty + 8 * r]);
}

// ---- 128x128-tile bf16 GEMM, 2-phase dbuf prefetch; z selects Q/K/V ----
// z<2 uses swapped-operand mfma (D transposed: lane = fixed s row, 4 consecutive n)
__global__ __launch_bounds__(256) void gemm_qkv(const unsigned short* __restrict__ Xb,
                                                const unsigned short* __restrict__ WtAll,
                                                unsigned short* __restrict__ Qb,
                                                unsigned short* __restrict__ Kh,
                                                unsigned short* __restrict__ Vb) {
  const int z = blockIdx.z;
  const unsigned short* Wt = WtAll + (size_t)z * (DIM * DIM);
  const int m0 = blockIdx.x * 128, n0 = blockIdx.y * 128;
  const int lane = threadIdx.x & 63, wave = threadIdx.x >> 6;
  const int wr = wave >> 1, wc = wave & 1;
  const int l15 = lane & 15, lg = lane >> 4;
  const int rowA = lane >> 2, colA = (lane & 3) * 8;
  const int sA = wave * 2;
  __shared__ __align__(16) unsigned short As[2][128 * 32], Bs[2][128 * 32];
  f32x4 acc[4][4] = {};

  auto STAGE = [&](int buf, int kt) {
    GLDS16(Xb + (size_t)(m0 + (sA + 0) * 16 + rowA) * DIM + kt + colA, &As[buf][(sA + 0) * 512]);
    GLDS16(Xb + (size_t)(m0 + (sA + 1) * 16 + rowA) * DIM + kt + colA, &As[buf][(sA + 1) * 512]);
    GLDS16(Wt + (size_t)(n0 + (sA + 0) * 16 + rowA) * DIM + kt + colA, &Bs[buf][(sA + 0) * 512]);
    GLDS16(Wt + (size_t)(n0 + (sA + 1) * 16 + rowA) * DIM + kt + colA, &Bs[buf][(sA + 1) * 512]);
  };

  STAGE(0, 0);
  __syncthreads();                       // drains prologue stage (vmcnt+lgkm)
  int cur = 0;
  for (int kt = 0; kt < DIM; kt += 32) {
    if (kt + 32 < DIM) STAGE(cur ^ 1, kt + 32);   // prefetch flies under compute
    bf16x8 af[4], bfr[4];
#pragma unroll
    for (int mi = 0; mi < 4; ++mi)
      af[mi] = *(const bf16x8*)&As[cur][(wr * 64 + mi * 16 + l15) * 32 + lg * 8];
#pragma unroll
    for (int ni = 0; ni < 4; ++ni)
      bfr[ni] = *(const bf16x8*)&Bs[cur][(wc * 64 + ni * 16 + l15) * 32 + lg * 8];
    if (z < 2) {
#pragma unroll
      for (int mi = 0; mi < 4; ++mi)
#pragma unroll
        for (int ni = 0; ni < 4; ++ni)
          acc[mi][ni] = __builtin_amdgcn_mfma_f32_16x16x32_bf16(bfr[ni], af[mi], acc[mi][ni], 0, 0, 0);
    } else {
#pragma unroll
      for (int mi = 0; mi < 4; ++mi)
#pragma unroll
        for (int ni = 0; ni < 4; ++ni)
          acc[mi][ni] = __builtin_amdgcn_mfma_f32_16x16x32_bf16(af[mi], bfr[ni], acc[mi][ni], 0, 0, 0);
    }
    __syncthreads();                     // drains prefetch + protects buf reuse
    cur ^= 1;
  }

  if (z == 0) {
    // swapped layout: lane holds s = ..+l15, n = nb..nb+3 -> ushort4
    const float scale = (float)(0.125 * 1.4426950408889634);
#pragma unroll
    for (int mi = 0; mi < 4; ++mi)
#pragma unroll
      for (int ni = 0; ni < 4; ++ni) {
        const int s = m0 + wr * 64 + mi * 16 + l15;
        const int nb = n0 + wc * 64 + ni * 16 + lg * 4;
        ushort4 v;
        v.x = f2bf(acc[mi][ni][0] * scale); v.y = f2bf(acc[mi][ni][1] * scale);
        v.z = f2bf(acc[mi][ni][2] * scale); v.w = f2bf(acc[mi][ni][3] * scale);
        *(ushort4*)&Qb[(size_t)s * DIM + nb] = v;
      }
  } else if (z == 1) {
    // K head-major: Kh[((b*16+h)*2048 + s)*64 + d], d..d+3 contiguous
#pragma unroll
    for (int mi = 0; mi < 4; ++mi)
#pragma unroll
      for (int ni = 0; ni < 4; ++ni) {
        const int s = m0 + wr * 64 + mi * 16 + l15;
        const int b = s >> 11, sl = s & 2047;
        const int nb = n0 + wc * 64 + ni * 16 + lg * 4;
        const int h = nb >> 6, d = nb & 63;
        ushort4 v;
        v.x = f2bf(acc[mi][ni][0]); v.y = f2bf(acc[mi][ni][1]);
        v.z = f2bf(acc[mi][ni][2]); v.w = f2bf(acc[mi][ni][3]);
        *(ushort4*)&Kh[((size_t)(b * 16 + h) * 2048 + sl) * 64 + d] = v;
      }
  } else {
    // V tiled (unswapped acc): Vb[(((b*16+h)*32 + t)*64 + d)*64 + si]
#pragma unroll
    for (int mi = 0; mi < 4; ++mi)
#pragma unroll
      for (int ni = 0; ni < 4; ++ni) {
        const int n = n0 + wc * 64 + ni * 16 + l15;
        const int h = n >> 6, d = n & 63;
        const int mb = m0 + wr * 64 + mi * 16 + lg * 4;
        const int b = mb >> 11, s = mb & 2047;
        const int t = s >> 6, si = s & 63;
        ushort4 v;
        v.x = f2bf(acc[mi][ni][0]); v.y = f2bf(acc[mi][ni][1]);
        v.z = f2bf(acc[mi][ni][2]); v.w = f2bf(acc[mi][ni][3]);
        *(ushort4*)&Vb[((((size_t)(b * 16 + h) * 32 + t) * 64 + d) * 64) + si] = v;
      }
  }
}

// ---- swapped-operand causal flash attention with LDS-staged K/V tiles ----
__global__ __launch_bounds__(256) void attn(const unsigned short* __restrict__ Qb,
                                            const unsigned short* __restrict__ Kh,
                                            const unsigned short* __restrict__ Vb,
                                            unsigned short* __restrict__ Cb) {
  const int bh = blockIdx.x;
  const int qt = (gridDim.y - 1) - blockIdx.y;        // heavy q-tiles first
  const int b = bh >> 4;
  const int tid = threadIdx.x;
  const int lane = tid & 63, wave = tid >> 6;
  const int l31 = lane & 31, hi = lane >> 5;
  const int swz = (l31 & 7) << 4;
  const int q_base = qt * 128 + wave * 32;
  const int q = q_base + l31;

  // [buf][ K: 0..8191 | V: 8192..16383 ], 8KB tile = 64 rows x 128B
  __shared__ __align__(16) char LDS[2][16384];

  // per-lane staging source offsets (bytes within an 8KB tile):
  // LDS linear pos L gets tile byte (row*128 + ((L&127) ^ ((row&7)<<4)))
  int soff0, soff1;
  {
    const int L0 = wave * 2048 + lane * 16;
    const int r0 = L0 >> 7;
    soff0 = r0 * 128 + ((L0 & 127) ^ ((r0 & 7) << 4));
    const int L1 = L0 + 1024;
    const int r1 = L1 >> 7;
    soff1 = r1 * 128 + ((L1 & 127) ^ ((r1 & 7) << 4));
  }
  const char* Kt0 = (const char*)Kh + ((size_t)bh * 2048) * 128;   // +t*8192 per tile
  const char* Vt0 = (const char*)Vb + ((size_t)bh * 32) * 8192;

  // Q B-frags: lane holds col q, k-elems hi*8..+8 per 16-k step
  const unsigned short* Qp = Qb + (size_t)(b * SEQ + q) * DIM + (bh & 15) * HDIM + hi * 8;
  bf16x8 qf[4];
#pragma unroll
  for (int ks = 0; ks < 4; ++ks) qf[ks] = *(const bf16x8*)(Qp + ks * 16);

  float m_r = -INFINITY, l_r = 0.f;
  f32x16 o0 = {}, o1 = {};

  const int n_tiles = 2 * qt + 2;
  int cur = 0;

  // prologue: stage tile 0
  {
    char* lK = &LDS[0][wave * 2048];
    char* lV = &LDS[0][8192 + wave * 2048];
    GLDS16(Kt0 + soff0, lK); GLDS16(Kt0 + soff1, lK + 1024);
    GLDS16(Vt0 + soff0, lV); GLDS16(Vt0 + soff1, lV + 1024);
  }
  __syncthreads();

  for (int t = 0; t < n_tiles; ++t) {
    const int kv0 = t << 6;
    // stage next tile into the other buffer (async; drains at syncthreads)
    if (t + 1 < n_tiles) {
      const char* kb = Kt0 + (size_t)(t + 1) * 8192;
      const char* vb = Vt0 + (size_t)(t + 1) * 8192;
      char* lK = &LDS[cur ^ 1][wave * 2048];
      char* lV = &LDS[cur ^ 1][8192 + wave * 2048];
      GLDS16(kb + soff0, lK); GLDS16(kb + soff1, lK + 1024);
      GLDS16(vb + soff0, lV); GLDS16(vb + soff1, lV + 1024);
    }

    if (kv0 <= q_base + 31) {   // wave-uniform: skip fully-masked tiles
      const char* Lb = &LDS[cur][0];
      // S^T[kv][q], two 32-kv halves
      f32x16 st0 = {}, st1 = {};
      __builtin_amdgcn_s_setprio(1);
#pragma unroll
      for (int ks = 0; ks < 4; ++ks) {
        const char* a = Lb + l31 * 128 + ((ks * 32 + hi * 16) ^ swz);
        bf16x8 kf0 = *(const bf16x8*)(a);
        bf16x8 kf1 = *(const bf16x8*)(a + 4096);
        st0 = __builtin_amdgcn_mfma_f32_32x32x16_bf16(kf0, qf[ks], st0, 0, 0, 0);
        st1 = __builtin_amdgcn_mfma_f32_32x32x16_bf16(kf1, qf[ks], st1, 0, 0, 0);
      }
      __builtin_amdgcn_s_setprio(0);

      // causal mask (diagonal tiles); kv offset = (r&3)+8*(r>>2)+4*hi (+32 st1)
      if (kv0 + 63 > q_base) {
        const int qm = q - kv0 - 4 * hi;
#pragma unroll
        for (int r = 0; r < 16; ++r) {
          const int c = (r & 3) + 8 * (r >> 2);
          if (c > qm)      st0[r] = -INFINITY;
          if (c + 32 > qm) st1[r] = -INFINITY;
        }
      }

      // lane-local row max + partner half via one shfl
      float tmax = st0[0];
#pragma unroll
      for (int r = 1; r < 16; ++r) tmax = fmaxf(tmax, st0[r]);
#pragma unroll
      for (int r = 0; r < 16; ++r) tmax = fmaxf(tmax, st1[r]);
      tmax = fmaxf(tmax, __shfl_xor(tmax, 32));

      // defer-max (T13)
      if (__any(!(tmax <= m_r + 8.0f))) {
        const float mn = fmaxf(m_r, tmax);
        const float al = exp2a(m_r - mn);
        m_r = mn;
        l_r *= al;
        o0 *= al;
        o1 *= al;
      }

      // P = exp2(S - m)
#pragma unroll
      for (int r = 0; r < 16; ++r) st0[r] = exp2a(st0[r] - m_r);
#pragma unroll
      for (int r = 0; r < 16; ++r) st1[r] = exp2a(st1[r] - m_r);
      float ps = 0.f;
#pragma unroll
      for (int r = 0; r < 16; ++r) ps += st0[r] + st1[r];
      ps += __shfl_xor(ps, 32);
      l_r += ps;

      // P -> bf16 B-frags via cvt_pk + permlane32_swap (T12)
      u32x4 pf[4];
      {
        unsigned a, bb;
        a = CVTPK(st0[0], st0[1]);   bb = CVTPK(st0[4], st0[5]);   pswap(a, bb); pf[0][0] = a; pf[0][2] = bb;
        a = CVTPK(st0[2], st0[3]);   bb = CVTPK(st0[6], st0[7]);   pswap(a, bb); pf[0][1] = a; pf[0][3] = bb;
        a = CVTPK(st0[8], st0[9]);   bb = CVTPK(st0[12], st0[13]); pswap(a, bb); pf[1][0] = a; pf[1][2] = bb;
        a = CVTPK(st0[10], st0[11]); bb = CVTPK(st0[14], st0[15]); pswap(a, bb); pf[1][1] = a; pf[1][3] = bb;
        a = CVTPK(st1[0], st1[1]);   bb = CVTPK(st1[4], st1[5]);   pswap(a, bb); pf[2][0] = a; pf[2][2] = bb;
        a = CVTPK(st1[2], st1[3]);   bb = CVTPK(st1[6], st1[7]);   pswap(a, bb); pf[2][1] = a; pf[2][3] = bb;
        a = CVTPK(st1[8], st1[9]);   bb = CVTPK(st1[12], st1[13]); pswap(a, bb); pf[3][0] = a; pf[3][2] = bb;
        a = CVTPK(st1[10], st1[11]); bb = CVTPK(st1[14], st1[15]); pswap(a, bb); pf[3][1] = a; pf[3][3] = bb;
      }

      // O^T += V · P^T  (A = V d-rows from LDS; B = P frags)
      __builtin_amdgcn_s_setprio(1);
#pragma unroll
      for (int ks = 0; ks < 4; ++ks) {
        const char* a = Lb + 8192 + l31 * 128 + ((ks * 32 + hi * 16) ^ swz);
        bf16x8 v0 = *(const bf16x8*)(a);
        bf16x8 v1 = *(const bf16x8*)(a + 4096);
        bf16x8 pb = __builtin_bit_cast(bf16x8, pf[ks]);
        o0 = __builtin_amdgcn_mfma_f32_32x32x16_bf16(v0, pb, o0, 0, 0, 0);
        o1 = __builtin_amdgcn_mfma_f32_32x32x16_bf16(v1, pb, o1, 0, 0, 0);
      }
      __builtin_amdgcn_s_setprio(0);
    }

    __syncthreads();   // drains this wave's GLDS16 (vmcnt) + orders buffer swap
    cur ^= 1;
  }

  // write C row q: d = dhalf*32 + (r&3)+8*(r>>2)+4*hi  -> 4-contiguous groups
  const float rl = 1.0f / l_r;
  unsigned short* Co = Cb + (size_t)(b * SEQ + q) * DIM + (bh & 15) * HDIM;
#pragma unroll
  for (int j = 0; j < 4; ++j) {
    ushort4 w0, w1;
    w0.x = f2bf(o0[4 * j + 0] * rl); w0.y = f2bf(o0[4 * j + 1] * rl);
    w0.z = f2bf(o0[4 * j + 2] * rl); w0.w = f2bf(o0[4 * j + 3] * rl);
    w1.x = f2bf(o1[4 * j + 0] * rl); w1.y = f2bf(o1[4 * j + 1] * rl);
    w1.z = f2bf(o1[4 * j + 2] * rl); w1.w = f2bf(o1[4 * j + 3] * rl);
    *(ushort4*)(Co + 8 * j + 4 * hi) = w0;
    *(ushort4*)(Co + 32 + 8 * j + 4 * hi) = w1;
  }
}

// ---- output projection: 2-phase dbuf + swapped operands, float4 stores ----
__global__ __launch_bounds__(256) void gemm_out(const unsigned short* __restrict__ Cb,
                                                const unsigned short* __restrict__ WtO,
                                                const float* __restrict__ bias,
                                                float* __restrict__ out) {
  const int m0 = blockIdx.x * 128, n0 = blockIdx.y * 128;
  const int lane = threadIdx.x & 63, wave = threadIdx.x >> 6;
  const int wr = wave >> 1, wc = wave & 1;
  const int l15 = lane & 15, lg = lane >> 4;
  const int rowA = lane >> 2, colA = (lane & 3) * 8;
  const int sA = wave * 2;
  __shared__ __align__(16) unsigned short As[2][128 * 32], Bs[2][128 * 32];
  f32x4 acc[4][4] = {};

  auto STAGE = [&](int buf, int kt) {
    GLDS16(Cb  + (size_t)(m0 + (sA + 0) * 16 + rowA) * DIM + kt + colA, &As[buf][(sA + 0) * 512]);
    GLDS16(Cb  + (size_t)(m0 + (sA + 1) * 16 + rowA) * DIM + kt + colA, &As[buf][(sA + 1) * 512]);
    GLDS16(WtO + (size_t)(n0 + (sA + 0) * 16 + rowA) * DIM + kt + colA, &Bs[buf][(sA + 0) * 512]);
    GLDS16(WtO + (size_t)(n0 + (sA + 1) * 16 + rowA) * DIM + kt + colA, &Bs[buf][(sA + 1) * 512]);
  };

  STAGE(0, 0);
  __syncthreads();
  int cur = 0;
  for (int kt = 0; kt < DIM; kt += 32) {
    if (kt + 32 < DIM) STAGE(cur ^ 1, kt + 32);
    bf16x8 af[4], bfr[4];
#pragma unroll
    for (int mi = 0; mi < 4; ++mi)
      af[mi] = *(const bf16x8*)&As[cur][(wr * 64 + mi * 16 + l15) * 32 + lg * 8];
#pragma unroll
    for (int ni = 0; ni < 4; ++ni)
      bfr[ni] = *(const bf16x8*)&Bs[cur][(wc * 64 + ni * 16 + l15) * 32 + lg * 8];
#pragma unroll
    for (int mi = 0; mi < 4; ++mi)
#pragma unroll
      for (int ni = 0; ni < 4; ++ni)
        acc[mi][ni] = __builtin_amdgcn_mfma_f32_16x16x32_bf16(bfr[ni], af[mi], acc[mi][ni], 0, 0, 0);
    __syncthreads();
    cur ^= 1;
  }

  // swapped layout: lane holds row s, cols nb..nb+3 -> float4 (+bias)
#pragma unroll
  for (int mi = 0; mi < 4; ++mi)
#pragma unroll
    for (int ni = 0; ni < 4; ++ni) {
      const int s = m0 + wr * 64 + mi * 16 + l15;
      const int nb = n0 + wc * 64 + ni * 16 + lg * 4;
      const float4 bv = *(const float4*)&bias[nb];
      float4 o;
      o.x = acc[mi][ni][0] + bv.x; o.y = acc[mi][ni][1] + bv.y;
      o.z = acc[mi][ni][2] + bv.z; o.w = acc[mi][ni][3] + bv.w;
      *(float4*)&out[(size_t)s * DIM + nb] = o;
    }
}

extern "C" void kernel_launch(void* const* d_in, const int* in_sizes, int n_in,
                              void* d_out, int out_size, void* d_ws, size_t ws_size,
                              hipStream_t stream) {
  const float* X  = (const float*)d_in[0];
  const float* WK = (const float*)d_in[1];
  const float* WQ = (const float*)d_in[2];
  const float* WV = (const float*)d_in[3];
  const float* WO = (const float*)d_in[4];
  const float* bo = (const float*)d_in[5];
  float* out = (float*)d_out;

  char* ws = (char*)d_ws;
  unsigned short* Xb    = (unsigned short*)(ws);                  // 16 MB (reused as Cb)
  unsigned short* WtAll = (unsigned short*)(ws + (16u << 20));    // 8 MB
  unsigned short* Qb    = (unsigned short*)(ws + (24u << 20));    // 16 MB
  unsigned short* Kh    = (unsigned short*)(ws + (40u << 20));    // 16 MB head-major K
  unsigned short* Vb    = (unsigned short*)(ws + (56u << 20));    // 16 MB tiled V
  unsigned short* Cb    = Xb;

  convert_x<<<8192, 256, 0, stream>>>((const float4*)X, (ushort4*)Xb);
  transpose_w<<<dim3(32, 32, 4), dim3(32, 8), 0, stream>>>(WQ, WK, WV, WO, WtAll);
  gemm_qkv<<<dim3(64, 8, 3), 256, 0, stream>>>(Xb, WtAll, Qb, Kh, Vb);
  attn<<<dim3(64, 16), 256, 0, stream>>>(Qb, Kh, Vb, Cb);
  gemm_out<<<dim3(64, 8), 256, 0, stream>>>(Cb, WtAll + 3u * 1048576u, bo, out);
}

// Round 10
// 262.049 us; speedup vs baseline: 1.0086x; 1.0086x over previous
//
#include <hip/hip_runtime.h>

// Fused MHA: X[4,2048,1024] fp32; W_K,W_Q,W_V,W_out[1024,1024]; b_out[1024].
//   1. convert_x:  X fp32 -> Xb bf16
//   2. transpose_w: W* fp32 [k][n] -> Wt bf16 [n][k]
//   3. gemm_qkv:   2-phase dbuf prefetch + slot-XOR LDS swizzle (T2, rule 21);
//                  Q (scaled 0.125*log2e, [s][1024]); K head-major Kh[bh][s][64];
//                  V tiled Vb[bh][t][d][s64]; Q/K swapped-operand mfma epilogue
//   4. attn:       swapped-operand flash attn; K/V tiles staged to LDS
//                  (coalesced global_load_lds, XOR-swizzled source), dbuf
//   5. gemm_out:   2-phase dbuf + swizzle + swapped-operand -> float4 stores
typedef float  f32x4  __attribute__((ext_vector_type(4)));
typedef float  f32x16 __attribute__((ext_vector_type(16)));
typedef __bf16 bf16x8 __attribute__((ext_vector_type(8)));
typedef unsigned int u32x4 __attribute__((ext_vector_type(4)));

#define DIM   1024
#define SEQ   2048
#define HDIM  64

static __device__ __forceinline__ unsigned short f2bf(float f) {
  unsigned int u = __builtin_bit_cast(unsigned int, f);
  u += 0x7fffu + ((u >> 16) & 1u);   // RNE
  return (unsigned short)(u >> 16);
}

static __device__ __forceinline__ float exp2a(float x) {
#if __has_builtin(__builtin_amdgcn_exp2f)
  return __builtin_amdgcn_exp2f(x);
#else
  return exp2f(x);
#endif
}

static __device__ __forceinline__ void pswap(unsigned& a, unsigned& b) {
#if __has_builtin(__builtin_amdgcn_permlane32_swap)
  auto r = __builtin_amdgcn_permlane32_swap(a, b, false, false);
  a = r[0]; b = r[1];
#else
  asm volatile("v_permlane32_swap_b32 %0, %1" : "+v"(a), "+v"(b));
#endif
}

#define CVTPK(lo_, hi_) ({ unsigned r_;                                                 \
  asm("v_cvt_pk_bf16_f32 %0, %1, %2" : "=v"(r_) : "v"(lo_), "v"(hi_)); r_; })

// async global->LDS, 16B per lane; lds dest = wave-uniform base + lane*16
#define GLDS16(g, l)                                                                    \
  __builtin_amdgcn_global_load_lds((__attribute__((address_space(1))) void*)(g),        \
                                   (__attribute__((address_space(3))) void*)(l), 16, 0, 0)

__global__ __launch_bounds__(256) void convert_x(const float4* __restrict__ X,
                                                 ushort4* __restrict__ Xb) {
  int i = blockIdx.x * 256 + threadIdx.x;
  float4 v = X[i];
  ushort4 o;
  o.x = f2bf(v.x); o.y = f2bf(v.y); o.z = f2bf(v.z); o.w = f2bf(v.w);
  Xb[i] = o;
}

__global__ __launch_bounds__(256) void transpose_w(const float* __restrict__ WQ,
                                                   const float* __restrict__ WK,
                                                   const float* __restrict__ WV,
                                                   const float* __restrict__ WO,
                                                   unsigned short* __restrict__ WtAll) {
  const int z = blockIdx.z;
  const float* W = (z == 0) ? WQ : (z == 1) ? WK : (z == 2) ? WV : WO;
  unsigned short* Wt = WtAll + (size_t)z * (DIM * DIM);
  __shared__ float tile[32][33];
  const int tx = threadIdx.x, ty = threadIdx.y;        // 32 x 8
  const int n0 = blockIdx.x * 32, k0 = blockIdx.y * 32;
#pragma unroll
  for (int r = 0; r < 4; ++r)
    tile[ty + 8 * r][tx] = W[(size_t)(k0 + ty + 8 * r) * DIM + n0 + tx];
  __syncthreads();
#pragma unroll
  for (int r = 0; r < 4; ++r)
    Wt[(size_t)(n0 + ty + 8 * r) * DIM + k0 + tx] = f2bf(tile[tx][ty + 8 * r]);
}

// ---- 128x128-tile bf16 GEMM, 2-phase dbuf + slot-XOR swizzle; z selects Q/K/V ----
// LDS rows are 64B (32 shorts); physical 16B slot p of row r holds source slot
// p ^ ((r>>1)&3). Staging pre-swizzles the GLOBAL source (linear LDS dest);
// fragment reads XOR the slot index. 8-way bank conflict -> 2-way (free).
__global__ __launch_bounds__(256) void gemm_qkv(const unsigned short* __restrict__ Xb,
                                                const unsigned short* __restrict__ WtAll,
                                                unsigned short* __restrict__ Qb,
                                                unsigned short* __restrict__ Kh,
                                                unsigned short* __restrict__ Vb) {
  const int z = blockIdx.z;
  const unsigned short* Wt = WtAll + (size_t)z * (DIM * DIM);
  const int m0 = blockIdx.x * 128, n0 = blockIdx.y * 128;
  const int lane = threadIdx.x & 63, wave = threadIdx.x >> 6;
  const int wr = wave >> 1, wc = wave & 1;
  const int l15 = lane & 15, lg = lane >> 4;
  const int rowA = lane >> 2;
  // staging: source col slot XORed by row parity-pair ((rT>>1)&3 == (rowA>>1)&3)
  const int colS = (((lane & 3) ^ ((rowA >> 1) & 3)) * 8);
  // reads: physical slot = lg ^ ((rT>>1)&3) == lg ^ ((l15>>1)&3)
  const int slotS = ((lg ^ ((l15 >> 1) & 3)) * 8);
  const int sA = wave * 2;
  __shared__ __align__(16) unsigned short As[2][128 * 32], Bs[2][128 * 32];
  f32x4 acc[4][4] = {};

  auto STAGE = [&](int buf, int kt) {
    GLDS16(Xb + (size_t)(m0 + (sA + 0) * 16 + rowA) * DIM + kt + colS, &As[buf][(sA + 0) * 512]);
    GLDS16(Xb + (size_t)(m0 + (sA + 1) * 16 + rowA) * DIM + kt + colS, &As[buf][(sA + 1) * 512]);
    GLDS16(Wt + (size_t)(n0 + (sA + 0) * 16 + rowA) * DIM + kt + colS, &Bs[buf][(sA + 0) * 512]);
    GLDS16(Wt + (size_t)(n0 + (sA + 1) * 16 + rowA) * DIM + kt + colS, &Bs[buf][(sA + 1) * 512]);
  };

  STAGE(0, 0);
  __syncthreads();                       // drains prologue stage (vmcnt+lgkm)
  int cur = 0;
  for (int kt = 0; kt < DIM; kt += 32) {
    if (kt + 32 < DIM) STAGE(cur ^ 1, kt + 32);   // prefetch flies under compute
    bf16x8 af[4], bfr[4];
#pragma unroll
    for (int mi = 0; mi < 4; ++mi)
      af[mi] = *(const bf16x8*)&As[cur][(wr * 64 + mi * 16 + l15) * 32 + slotS];
#pragma unroll
    for (int ni = 0; ni < 4; ++ni)
      bfr[ni] = *(const bf16x8*)&Bs[cur][(wc * 64 + ni * 16 + l15) * 32 + slotS];
    if (z < 2) {
#pragma unroll
      for (int mi = 0; mi < 4; ++mi)
#pragma unroll
        for (int ni = 0; ni < 4; ++ni)
          acc[mi][ni] = __builtin_amdgcn_mfma_f32_16x16x32_bf16(bfr[ni], af[mi], acc[mi][ni], 0, 0, 0);
    } else {
#pragma unroll
      for (int mi = 0; mi < 4; ++mi)
#pragma unroll
        for (int ni = 0; ni < 4; ++ni)
          acc[mi][ni] = __builtin_amdgcn_mfma_f32_16x16x32_bf16(af[mi], bfr[ni], acc[mi][ni], 0, 0, 0);
    }
    __syncthreads();                     // drains prefetch + protects buf reuse
    cur ^= 1;
  }

  if (z == 0) {
    // swapped layout: lane holds s = ..+l15, n = nb..nb+3 -> ushort4
    const float scale = (float)(0.125 * 1.4426950408889634);
#pragma unroll
    for (int mi = 0; mi < 4; ++mi)
#pragma unroll
      for (int ni = 0; ni < 4; ++ni) {
        const int s = m0 + wr * 64 + mi * 16 + l15;
        const int nb = n0 + wc * 64 + ni * 16 + lg * 4;
        ushort4 v;
        v.x = f2bf(acc[mi][ni][0] * scale); v.y = f2bf(acc[mi][ni][1] * scale);
        v.z = f2bf(acc[mi][ni][2] * scale); v.w = f2bf(acc[mi][ni][3] * scale);
        *(ushort4*)&Qb[(size_t)s * DIM + nb] = v;
      }
  } else if (z == 1) {
    // K head-major: Kh[((b*16+h)*2048 + s)*64 + d], d..d+3 contiguous
#pragma unroll
    for (int mi = 0; mi < 4; ++mi)
#pragma unroll
      for (int ni = 0; ni < 4; ++ni) {
        const int s = m0 + wr * 64 + mi * 16 + l15;
        const int b = s >> 11, sl = s & 2047;
        const int nb = n0 + wc * 64 + ni * 16 + lg * 4;
        const int h = nb >> 6, d = nb & 63;
        ushort4 v;
        v.x = f2bf(acc[mi][ni][0]); v.y = f2bf(acc[mi][ni][1]);
        v.z = f2bf(acc[mi][ni][2]); v.w = f2bf(acc[mi][ni][3]);
        *(ushort4*)&Kh[((size_t)(b * 16 + h) * 2048 + sl) * 64 + d] = v;
      }
  } else {
    // V tiled (unswapped acc): Vb[(((b*16+h)*32 + t)*64 + d)*64 + si]
#pragma unroll
    for (int mi = 0; mi < 4; ++mi)
#pragma unroll
      for (int ni = 0; ni < 4; ++ni) {
        const int n = n0 + wc * 64 + ni * 16 + l15;
        const int h = n >> 6, d = n & 63;
        const int mb = m0 + wr * 64 + mi * 16 + lg * 4;
        const int b = mb >> 11, s = mb & 2047;
        const int t = s >> 6, si = s & 63;
        ushort4 v;
        v.x = f2bf(acc[mi][ni][0]); v.y = f2bf(acc[mi][ni][1]);
        v.z = f2bf(acc[mi][ni][2]); v.w = f2bf(acc[mi][ni][3]);
        *(ushort4*)&Vb[((((size_t)(b * 16 + h) * 32 + t) * 64 + d) * 64) + si] = v;
      }
  }
}

// ---- swapped-operand causal flash attention with LDS-staged K/V tiles ----
__global__ __launch_bounds__(256) void attn(const unsigned short* __restrict__ Qb,
                                            const unsigned short* __restrict__ Kh,
                                            const unsigned short* __restrict__ Vb,
                                            unsigned short* __restrict__ Cb) {
  const int bh = blockIdx.x;
  const int qt = (gridDim.y - 1) - blockIdx.y;        // heavy q-tiles first
  const int b = bh >> 4;
  const int tid = threadIdx.x;
  const int lane = tid & 63, wave = tid >> 6;
  const int l31 = lane & 31, hi = lane >> 5;
  const int swz = (l31 & 7) << 4;
  const int q_base = qt * 128 + wave * 32;
  const int q = q_base + l31;

  // [buf][ K: 0..8191 | V: 8192..16383 ], 8KB tile = 64 rows x 128B
  __shared__ __align__(16) char LDS[2][16384];

  // per-lane staging source offsets (bytes within an 8KB tile):
  // LDS linear pos L gets tile byte (row*128 + ((L&127) ^ ((row&7)<<4)))
  int soff0, soff1;
  {
    const int L0 = wave * 2048 + lane * 16;
    const int r0 = L0 >> 7;
    soff0 = r0 * 128 + ((L0 & 127) ^ ((r0 & 7) << 4));
    const int L1 = L0 + 1024;
    const int r1 = L1 >> 7;
    soff1 = r1 * 128 + ((L1 & 127) ^ ((r1 & 7) << 4));
  }
  const char* Kt0 = (const char*)Kh + ((size_t)bh * 2048) * 128;   // +t*8192 per tile
  const char* Vt0 = (const char*)Vb + ((size_t)bh * 32) * 8192;

  // Q B-frags: lane holds col q, k-elems hi*8..+8 per 16-k step
  const unsigned short* Qp = Qb + (size_t)(b * SEQ + q) * DIM + (bh & 15) * HDIM + hi * 8;
  bf16x8 qf[4];
#pragma unroll
  for (int ks = 0; ks < 4; ++ks) qf[ks] = *(const bf16x8*)(Qp + ks * 16);

  float m_r = -INFINITY, l_r = 0.f;
  f32x16 o0 = {}, o1 = {};

  const int n_tiles = 2 * qt + 2;
  int cur = 0;

  // prologue: stage tile 0
  {
    char* lK = &LDS[0][wave * 2048];
    char* lV = &LDS[0][8192 + wave * 2048];
    GLDS16(Kt0 + soff0, lK); GLDS16(Kt0 + soff1, lK + 1024);
    GLDS16(Vt0 + soff0, lV); GLDS16(Vt0 + soff1, lV + 1024);
  }
  __syncthreads();

  for (int t = 0; t < n_tiles; ++t) {
    const int kv0 = t << 6;
    // stage next tile into the other buffer (async; drains at syncthreads)
    if (t + 1 < n_tiles) {
      const char* kb = Kt0 + (size_t)(t + 1) * 8192;
      const char* vb = Vt0 + (size_t)(t + 1) * 8192;
      char* lK = &LDS[cur ^ 1][wave * 2048];
      char* lV = &LDS[cur ^ 1][8192 + wave * 2048];
      GLDS16(kb + soff0, lK); GLDS16(kb + soff1, lK + 1024);
      GLDS16(vb + soff0, lV); GLDS16(vb + soff1, lV + 1024);
    }

    if (kv0 <= q_base + 31) {   // wave-uniform: skip fully-masked tiles
      const char* Lb = &LDS[cur][0];
      // S^T[kv][q], two 32-kv halves
      f32x16 st0 = {}, st1 = {};
      __builtin_amdgcn_s_setprio(1);
#pragma unroll
      for (int ks = 0; ks < 4; ++ks) {
        const char* a = Lb + l31 * 128 + ((ks * 32 + hi * 16) ^ swz);
        bf16x8 kf0 = *(const bf16x8*)(a);
        bf16x8 kf1 = *(const bf16x8*)(a + 4096);
        st0 = __builtin_amdgcn_mfma_f32_32x32x16_bf16(kf0, qf[ks], st0, 0, 0, 0);
        st1 = __builtin_amdgcn_mfma_f32_32x32x16_bf16(kf1, qf[ks], st1, 0, 0, 0);
      }
      __builtin_amdgcn_s_setprio(0);

      // causal mask (diagonal tiles); kv offset = (r&3)+8*(r>>2)+4*hi (+32 st1)
      if (kv0 + 63 > q_base) {
        const int qm = q - kv0 - 4 * hi;
#pragma unroll
        for (int r = 0; r < 16; ++r) {
          const int c = (r & 3) + 8 * (r >> 2);
          if (c > qm)      st0[r] = -INFINITY;
          if (c + 32 > qm) st1[r] = -INFINITY;
        }
      }

      // lane-local row max + partner half via one shfl
      float tmax = st0[0];
#pragma unroll
      for (int r = 1; r < 16; ++r) tmax = fmaxf(tmax, st0[r]);
#pragma unroll
      for (int r = 0; r < 16; ++r) tmax = fmaxf(tmax, st1[r]);
      tmax = fmaxf(tmax, __shfl_xor(tmax, 32));

      // defer-max (T13)
      if (__any(!(tmax <= m_r + 8.0f))) {
        const float mn = fmaxf(m_r, tmax);
        const float al = exp2a(m_r - mn);
        m_r = mn;
        l_r *= al;
        o0 *= al;
        o1 *= al;
      }

      // P = exp2(S - m)
#pragma unroll
      for (int r = 0; r < 16; ++r) st0[r] = exp2a(st0[r] - m_r);
#pragma unroll
      for (int r = 0; r < 16; ++r) st1[r] = exp2a(st1[r] - m_r);
      float ps = 0.f;
#pragma unroll
      for (int r = 0; r < 16; ++r) ps += st0[r] + st1[r];
      ps += __shfl_xor(ps, 32);
      l_r += ps;

      // P -> bf16 B-frags via cvt_pk + permlane32_swap (T12)
      u32x4 pf[4];
      {
        unsigned a, bb;
        a = CVTPK(st0[0], st0[1]);   bb = CVTPK(st0[4], st0[5]);   pswap(a, bb); pf[0][0] = a; pf[0][2] = bb;
        a = CVTPK(st0[2], st0[3]);   bb = CVTPK(st0[6], st0[7]);   pswap(a, bb); pf[0][1] = a; pf[0][3] = bb;
        a = CVTPK(st0[8], st0[9]);   bb = CVTPK(st0[12], st0[13]); pswap(a, bb); pf[1][0] = a; pf[1][2] = bb;
        a = CVTPK(st0[10], st0[11]); bb = CVTPK(st0[14], st0[15]); pswap(a, bb); pf[1][1] = a; pf[1][3] = bb;
        a = CVTPK(st1[0], st1[1]);   bb = CVTPK(st1[4], st1[5]);   pswap(a, bb); pf[2][0] = a; pf[2][2] = bb;
        a = CVTPK(st1[2], st1[3]);   bb = CVTPK(st1[6], st1[7]);   pswap(a, bb); pf[2][1] = a; pf[2][3] = bb;
        a = CVTPK(st1[8], st1[9]);   bb = CVTPK(st1[12], st1[13]); pswap(a, bb); pf[3][0] = a; pf[3][2] = bb;
        a = CVTPK(st1[10], st1[11]); bb = CVTPK(st1[14], st1[15]); pswap(a, bb); pf[3][1] = a; pf[3][3] = bb;
      }

      // O^T += V · P^T  (A = V d-rows from LDS; B = P frags)
      __builtin_amdgcn_s_setprio(1);
#pragma unroll
      for (int ks = 0; ks < 4; ++ks) {
        const char* a = Lb + 8192 + l31 * 128 + ((ks * 32 + hi * 16) ^ swz);
        bf16x8 v0 = *(const bf16x8*)(a);
        bf16x8 v1 = *(const bf16x8*)(a + 4096);
        bf16x8 pb = __builtin_bit_cast(bf16x8, pf[ks]);
        o0 = __builtin_amdgcn_mfma_f32_32x32x16_bf16(v0, pb, o0, 0, 0, 0);
        o1 = __builtin_amdgcn_mfma_f32_32x32x16_bf16(v1, pb, o1, 0, 0, 0);
      }
      __builtin_amdgcn_s_setprio(0);
    }

    __syncthreads();   // drains this wave's GLDS16 (vmcnt) + orders buffer swap
    cur ^= 1;
  }

  // write C row q: d = dhalf*32 + (r&3)+8*(r>>2)+4*hi  -> 4-contiguous groups
  const float rl = 1.0f / l_r;
  unsigned short* Co = Cb + (size_t)(b * SEQ + q) * DIM + (bh & 15) * HDIM;
#pragma unroll
  for (int j = 0; j < 4; ++j) {
    ushort4 w0, w1;
    w0.x = f2bf(o0[4 * j + 0] * rl); w0.y = f2bf(o0[4 * j + 1] * rl);
    w0.z = f2bf(o0[4 * j + 2] * rl); w0.w = f2bf(o0[4 * j + 3] * rl);
    w1.x = f2bf(o1[4 * j + 0] * rl); w1.y = f2bf(o1[4 * j + 1] * rl);
    w1.z = f2bf(o1[4 * j + 2] * rl); w1.w = f2bf(o1[4 * j + 3] * rl);
    *(ushort4*)(Co + 8 * j + 4 * hi) = w0;
    *(ushort4*)(Co + 32 + 8 * j + 4 * hi) = w1;
  }
}

// ---- output projection: 2-phase dbuf + swizzle + swapped operands ----
__global__ __launch_bounds__(256) void gemm_out(const unsigned short* __restrict__ Cb,
                                                const unsigned short* __restrict__ WtO,
                                                const float* __restrict__ bias,
                                                float* __restrict__ out) {
  const int m0 = blockIdx.x * 128, n0 = blockIdx.y * 128;
  const int lane = threadIdx.x & 63, wave = threadIdx.x >> 6;
  const int wr = wave >> 1, wc = wave & 1;
  const int l15 = lane & 15, lg = lane >> 4;
  const int rowA = lane >> 2;
  const int colS = (((lane & 3) ^ ((rowA >> 1) & 3)) * 8);
  const int slotS = ((lg ^ ((l15 >> 1) & 3)) * 8);
  const int sA = wave * 2;
  __shared__ __align__(16) unsigned short As[2][128 * 32], Bs[2][128 * 32];
  f32x4 acc[4][4] = {};

  auto STAGE = [&](int buf, int kt) {
    GLDS16(Cb  + (size_t)(m0 + (sA + 0) * 16 + rowA) * DIM + kt + colS, &As[buf][(sA + 0) * 512]);
    GLDS16(Cb  + (size_t)(m0 + (sA + 1) * 16 + rowA) * DIM + kt + colS, &As[buf][(sA + 1) * 512]);
    GLDS16(WtO + (size_t)(n0 + (sA + 0) * 16 + rowA) * DIM + kt + colS, &Bs[buf][(sA + 0) * 512]);
    GLDS16(WtO + (size_t)(n0 + (sA + 1) * 16 + rowA) * DIM + kt + colS, &Bs[buf][(sA + 1) * 512]);
  };

  STAGE(0, 0);
  __syncthreads();
  int cur = 0;
  for (int kt = 0; kt < DIM; kt += 32) {
    if (kt + 32 < DIM) STAGE(cur ^ 1, kt + 32);
    bf16x8 af[4], bfr[4];
#pragma unroll
    for (int mi = 0; mi < 4; ++mi)
      af[mi] = *(const bf16x8*)&As[cur][(wr * 64 + mi * 16 + l15) * 32 + slotS];
#pragma unroll
    for (int ni = 0; ni < 4; ++ni)
      bfr[ni] = *(const bf16x8*)&Bs[cur][(wc * 64 + ni * 16 + l15) * 32 + slotS];
#pragma unroll
    for (int mi = 0; mi < 4; ++mi)
#pragma unroll
      for (int ni = 0; ni < 4; ++ni)
        acc[mi][ni] = __builtin_amdgcn_mfma_f32_16x16x32_bf16(bfr[ni], af[mi], acc[mi][ni], 0, 0, 0);
    __syncthreads();
    cur ^= 1;
  }

  // swapped layout: lane holds row s, cols nb..nb+3 -> float4 (+bias)
#pragma unroll
  for (int mi = 0; mi < 4; ++mi)
#pragma unroll
    for (int ni = 0; ni < 4; ++ni) {
      const int s = m0 + wr * 64 + mi * 16 + l15;
      const int nb = n0 + wc * 64 + ni * 16 + lg * 4;
      const float4 bv = *(const float4*)&bias[nb];
      float4 o;
      o.x = acc[mi][ni][0] + bv.x; o.y = acc[mi][ni][1] + bv.y;
      o.z = acc[mi][ni][2] + bv.z; o.w = acc[mi][ni][3] + bv.w;
      *(float4*)&out[(size_t)s * DIM + nb] = o;
    }
}

extern "C" void kernel_launch(void* const* d_in, const int* in_sizes, int n_in,
                              void* d_out, int out_size, void* d_ws, size_t ws_size,
                              hipStream_t stream) {
  const float* X  = (const float*)d_in[0];
  const float* WK = (const float*)d_in[1];
  const float* WQ = (const float*)d_in[2];
  const float* WV = (const float*)d_in[3];
  const float* WO = (const float*)d_in[4];
  const float* bo = (const float*)d_in[5];
  float* out = (float*)d_out;

  char* ws = (char*)d_ws;
  unsigned short* Xb    = (unsigned short*)(ws);                  // 16 MB (reused as Cb)
  unsigned short* WtAll = (unsigned short*)(ws + (16u << 20));    // 8 MB
  unsigned short* Qb    = (unsigned short*)(ws + (24u << 20));    // 16 MB
  unsigned short* Kh    = (unsigned short*)(ws + (40u << 20));    // 16 MB head-major K
  unsigned short* Vb    = (unsigned short*)(ws + (56u << 20));    // 16 MB tiled V
  unsigned short* Cb    = Xb;

  convert_x<<<8192, 256, 0, stream>>>((const float4*)X, (ushort4*)Xb);
  transpose_w<<<dim3(32, 32, 4), dim3(32, 8), 0, stream>>>(WQ, WK, WV, WO, WtAll);
  gemm_qkv<<<dim3(64, 8, 3), 256, 0, stream>>>(Xb, WtAll, Qb, Kh, Vb);
  attn<<<dim3(64, 16), 256, 0, stream>>>(Qb, Kh, Vb, Cb);
  gemm_out<<<dim3(64, 8), 256, 0, stream>>>(Cb, WtAll + 3u * 1048576u, bo, out);
}